// Round 11
// baseline (626.989 us; speedup 1.0000x reference)
//
#include <hip/hip_runtime.h>
#include <cstdint>
#include <cstddef>

#define H      640
#define RH     256
#define NE     5
#define NA     40          // NE * rank
#define NTOK   32768
#define SCAL   2.0f        // alpha/rank = 16/8
#define BK     16
#define BM     32          // tokens/block; grid 1024 -> 4 blocks/CU resident
#define NT     (H / BK)    // 40 K-tiles

__device__ __forceinline__ float4 ld4(const float* p) {
    return *reinterpret_cast<const float4*>(p);
}

// ---------------------------------------------------------------------------
// Kernel 1: router (x@W1 -> silu -> @W2 -> softmax -> top2) + low = x@A.
// R3's exact loop/tile (2-token x 16-col, 64 VGPR proven) K-SPLIT over two
// 256-thread groups in one 512-thread block: group g computes kk in
// [8g, 8g+8) of every staged BK=16 tile (same LDS tiles, no duplication),
// then a 3-round LDS reduce folds group1 partials into group0 before R3's
// unchanged epilogue. Same work, same 35.3 KB LDS (4 blocks/CU), grid 1024
// exact -- but 32 waves/CU (8/SIMD) vs R3's 16: attacks the ~38% VALU idle
// (latency/barrier convoys) that capped R3 at 62%.
// __launch_bounds__(512,8) caps VGPR at 64 = R3's measured footprint.
// ---------------------------------------------------------------------------
__global__ __launch_bounds__(512, 8)
void k_router(const float* __restrict__ x, const float* __restrict__ W1,
              const float* __restrict__ b1v, const float* __restrict__ W2,
              const float* __restrict__ b2v, const float* __restrict__ A,
              float* __restrict__ route_c, int* __restrict__ route_idx)
{
    __shared__ float ws[BK][RH];        // 16 KB (aliased as reduce scratch)
    __shared__ float xs[BM][20];        // 2.56 KB
    __shared__ float as_[BK][64];       // 4 KB (cols 40..63 garbage)
    __shared__ float w2s[RH * NE];      // 5 KB
    __shared__ float b1s[RH];           // 1 KB
    __shared__ float low_lds[BM][NA];   // 5.12 KB
    __shared__ float logit_lds[BM][8];  // 1 KB
    float (*red)[16] = reinterpret_cast<float (*)[16]>(&ws[0][0]); // 16 KB

    const int tid  = threadIdx.x;
    const int grp  = tid >> 8;          // 0/1: K-half owner
    const int lt   = tid & 255;         // R3-role local tid
    const int row0 = blockIdx.x * BM;
    const int tm   = lt >> 4;           // 16 groups x 2 tokens
    const int tn   = lt & 15;           // 16 col-groups

    // staging maps (512 threads)
    const int xrow = tid >> 2, xc = tid & 3;       // x: 128 f4 (tid<128)
    const int arow = tid / 10, ac4 = tid % 10;     // A: 160 f4 (tid<160)
    const int ae = ac4 >> 1, ar0 = (ac4 & 1) * 4;
    const float* xsrc = x + (size_t)(row0 + xrow) * H + xc * 4;
    const float* asrc = A + ((size_t)ae * H + arow) * 8 + ar0;

    for (int i = tid; i < RH * NE; i += 512) w2s[i] = W2[i];
    if (tid < RH) b1s[tid] = b1v[tid];

    float acc[2][16];
    #pragma unroll
    for (int j = 0; j < 2; j++)
        #pragma unroll
        for (int c = 0; c < 16; c++) acc[j][c] = 0.f;
    float accl[2][4];
    #pragma unroll
    for (int j = 0; j < 2; j++)
        #pragma unroll
        for (int c = 0; c < 4; c++) accl[j][c] = 0.f;

    const int kb = grp * 8;             // this group's kk base within a tile

    for (int t = 0; t < NT; ++t) {
        const int k0 = t * BK;
        __syncthreads();
        // stage x tile [32][16]
        if (tid < 128)
            *reinterpret_cast<float4*>(&xs[xrow][xc * 4]) = ld4(xsrc + k0);
        // stage W1 tile [16][256]: 1024 f4 over 512 threads (linear)
        #pragma unroll
        for (int i = 0; i < 2; i++) {
            int idx4 = tid + i * 512;
            int row = idx4 >> 6, c4 = idx4 & 63;
            *reinterpret_cast<float4*>(&ws[row][c4 * 4]) =
                ld4(W1 + (size_t)(k0 + row) * RH + c4 * 4);
        }
        // stage A tile [16][40 real]
        if (tid < 160)
            *reinterpret_cast<float4*>(&as_[arow][ac4 * 4]) =
                ld4(asrc + (size_t)k0 * 8);
        __syncthreads();

        #pragma unroll
        for (int kk4 = 0; kk4 < 8; kk4 += 4) {
            const int kz = kb + kk4;    // wave-uniform (grp uniform per wave)
            float4 xa0 = *reinterpret_cast<const float4*>(&xs[2 * tm + 0][kz]);
            float4 xa1 = *reinterpret_cast<const float4*>(&xs[2 * tm + 1][kz]);
            #pragma unroll
            for (int u = 0; u < 4; u++) {
                float bb[16];
                #pragma unroll
                for (int q = 0; q < 4; q++)
                    *reinterpret_cast<float4*>(&bb[q * 4]) =
                        *reinterpret_cast<const float4*>(&ws[kz + u][(tn + 16 * q) * 4]);
                float lb[4];
                *reinterpret_cast<float4*>(lb) =
                    *reinterpret_cast<const float4*>(&as_[kz + u][tn * 4]);
                float av0 = (u == 0) ? xa0.x : (u == 1) ? xa0.y : (u == 2) ? xa0.z : xa0.w;
                float av1 = (u == 0) ? xa1.x : (u == 1) ? xa1.y : (u == 2) ? xa1.z : xa1.w;
                #pragma unroll
                for (int c = 0; c < 16; c++) {
                    acc[0][c] = fmaf(av0, bb[c], acc[0][c]);
                    acc[1][c] = fmaf(av1, bb[c], acc[1][c]);
                }
                #pragma unroll
                for (int c = 0; c < 4; c++) {
                    accl[0][c] = fmaf(av0, lb[c], accl[0][c]);
                    accl[1][c] = fmaf(av1, lb[c], accl[1][c]);
                }
            }
        }
    }

    // ---- cross-group K-reduce via ws-aliased scratch (3 rounds) ----
    __syncthreads();                     // all ws reads done
    if (grp) {
        #pragma unroll
        for (int q = 0; q < 4; q++)
            *reinterpret_cast<float4*>(&red[lt][q * 4]) =
                *reinterpret_cast<float4*>(&acc[0][q * 4]);
    }
    __syncthreads();
    if (!grp) {
        #pragma unroll
        for (int c = 0; c < 16; c++) acc[0][c] += red[lt][c];
    }
    __syncthreads();
    if (grp) {
        #pragma unroll
        for (int q = 0; q < 4; q++)
            *reinterpret_cast<float4*>(&red[lt][q * 4]) =
                *reinterpret_cast<float4*>(&acc[1][q * 4]);
    }
    __syncthreads();
    if (!grp) {
        #pragma unroll
        for (int c = 0; c < 16; c++) acc[1][c] += red[lt][c];
    }
    __syncthreads();
    if (grp) {
        *reinterpret_cast<float4*>(&red[lt][0]) = *reinterpret_cast<float4*>(&accl[0][0]);
        *reinterpret_cast<float4*>(&red[lt][4]) = *reinterpret_cast<float4*>(&accl[1][0]);
    }
    __syncthreads();
    if (!grp) {
        #pragma unroll
        for (int c = 0; c < 4; c++) { accl[0][c] += red[lt][c]; accl[1][c] += red[lt][4 + c]; }
    }
    __syncthreads();

    // ---- epilogue: group 0 only (R3 verbatim, lt == tid here) ----
    if (tid < 256) {
        if (tn < 10) {
            #pragma unroll
            for (int j = 0; j < 2; j++)
                *reinterpret_cast<float4*>(&low_lds[2 * tm + j][tn * 4]) =
                    *reinterpret_cast<float4*>(&accl[j][0]);
        }

        float part[2][5];
        #pragma unroll
        for (int j = 0; j < 2; j++)
            #pragma unroll
            for (int e = 0; e < 5; e++) part[j][e] = 0.f;

        #pragma unroll
        for (int q = 0; q < 4; q++)
            #pragma unroll
            for (int i4 = 0; i4 < 4; i4++) {
                int col = (tn + 16 * q) * 4 + i4;
                float bbias = b1s[col];
                float w2r[5];
                #pragma unroll
                for (int e = 0; e < 5; e++) w2r[e] = w2s[col * 5 + e];
                #pragma unroll
                for (int j = 0; j < 2; j++) {
                    float v = acc[j][q * 4 + i4] + bbias;
                    float s = __fdividef(v, 1.f + __expf(-v));   // silu
                    #pragma unroll
                    for (int e = 0; e < 5; e++) part[j][e] = fmaf(s, w2r[e], part[j][e]);
                }
            }

        #pragma unroll
        for (int j = 0; j < 2; j++)
            #pragma unroll
            for (int e = 0; e < 5; e++) {
                float v = part[j][e];
                v += __shfl_xor(v, 1);
                v += __shfl_xor(v, 2);
                v += __shfl_xor(v, 4);
                v += __shfl_xor(v, 8);
                part[j][e] = v;
            }

        if (tn == 0) {
            #pragma unroll
            for (int j = 0; j < 2; j++)
                #pragma unroll
                for (int e = 0; e < 5; e++) logit_lds[2 * tm + j][e] = part[j][e];
        }
    }
    __syncthreads();

    // one thread per token: top-2 + route_c write
    if (tid < BM) {
        const int tk = tid;
        float l0 = logit_lds[tk][0] + b2v[0];
        float l1 = logit_lds[tk][1] + b2v[1];
        float l2 = logit_lds[tk][2] + b2v[2];
        float l3 = logit_lds[tk][3] + b2v[3];
        float l4 = logit_lds[tk][4] + b2v[4];
        int   i0 = 0;  float m0 = l0;
        int   i1 = -1; float m1 = -3.4e38f;
        if (l1 > m0) { m1 = m0; i1 = i0; m0 = l1; i0 = 1; } else if (l1 > m1) { m1 = l1; i1 = 1; }
        if (l2 > m0) { m1 = m0; i1 = i0; m0 = l2; i0 = 2; } else if (l2 > m1) { m1 = l2; i1 = 2; }
        if (l3 > m0) { m1 = m0; i1 = i0; m0 = l3; i0 = 3; } else if (l3 > m1) { m1 = l3; i1 = 3; }
        if (l4 > m0) { m1 = m0; i1 = i0; m0 = l4; i0 = 4; } else if (l4 > m1) { m1 = l4; i1 = 4; }
        float w1r = __expf(m1 - m0);
        float inv = __fdividef(1.f, 1.f + w1r);
        float c0 = inv * SCAL;
        float c1 = w1r * inv * SCAL;
        int gt = row0 + tk;
        #pragma unroll
        for (int r4 = 0; r4 < 2; r4++) {
            float4 v0 = ld4(&low_lds[tk][i0 * 8 + r4 * 4]);
            v0.x *= c0; v0.y *= c0; v0.z *= c0; v0.w *= c0;
            *reinterpret_cast<float4*>(&route_c[(size_t)gt * 16 + r4 * 4]) = v0;
            float4 v1 = ld4(&low_lds[tk][i1 * 8 + r4 * 4]);
            v1.x *= c1; v1.y *= c1; v1.z *= c1; v1.w *= c1;
            *reinterpret_cast<float4*>(&route_c[(size_t)gt * 16 + 8 + r4 * 4]) = v1;
        }
        route_idx[gt * 2 + 0] = i0;
        route_idx[gt * 2 + 1] = i1;
    }
}

// ---------------------------------------------------------------------------
// Kernel 2: out[t] = base[t] + sum_j c[t][j] * Bm_row[idx_j][:]
// All of Bm (40x640 f32 = 102.4 KB) staged in LDS. 512 thr (8 waves), one
// wave per token at a time; grid = 256 blocks * 128 tokens. ~20-27 us, at
// the 168 MB HBM floor (base+out) -- unchanged.
// ---------------------------------------------------------------------------
__global__ __launch_bounds__(512)
void k_combine(const float* __restrict__ base, const float* __restrict__ Bm,
               const float* __restrict__ route_c, const int* __restrict__ route_idx,
               float* __restrict__ out)
{
    __shared__ float bs[NA][H];
    const int tid = threadIdx.x;
    for (int i4 = tid; i4 < NA * H / 4; i4 += 512)
        reinterpret_cast<float4*>(&bs[0][0])[i4] = reinterpret_cast<const float4*>(Bm)[i4];
    __syncthreads();

    const int w    = tid >> 6;
    const int lane = tid & 63;

    for (int it = 0; it < 16; it++) {
        int t = blockIdx.x * 128 + w * 16 + it;
        t = __builtin_amdgcn_readfirstlane(t);
        const int e0 = route_idx[t * 2 + 0];
        const int e1 = route_idx[t * 2 + 1];
        float cc[16];
        #pragma unroll
        for (int q = 0; q < 4; q++)
            *reinterpret_cast<float4*>(&cc[q * 4]) = ld4(route_c + (size_t)t * 16 + q * 4);

        const float* brow0 = &bs[e0 * 8][0];
        const float* brow1 = &bs[e1 * 8][0];
        const float* bp = base + (size_t)t * H;
        float*       op = out  + (size_t)t * H;

        #pragma unroll
        for (int i = 0; i < 2; i++) {
            int h = i * 256 + lane * 4;
            float4 a = ld4(bp + h);
            #pragma unroll
            for (int j = 0; j < 8; j++) {
                float4 bv = *reinterpret_cast<const float4*>(brow0 + j * H + h);
                a.x = fmaf(cc[j], bv.x, a.x); a.y = fmaf(cc[j], bv.y, a.y);
                a.z = fmaf(cc[j], bv.z, a.z); a.w = fmaf(cc[j], bv.w, a.w);
            }
            #pragma unroll
            for (int j = 0; j < 8; j++) {
                float4 bv = *reinterpret_cast<const float4*>(brow1 + j * H + h);
                a.x = fmaf(cc[8 + j], bv.x, a.x); a.y = fmaf(cc[8 + j], bv.y, a.y);
                a.z = fmaf(cc[8 + j], bv.z, a.z); a.w = fmaf(cc[8 + j], bv.w, a.w);
            }
            *reinterpret_cast<float4*>(op + h) = a;
        }
        {
            int h = 512 + lane * 2;
            float2 a = *reinterpret_cast<const float2*>(bp + h);
            #pragma unroll
            for (int j = 0; j < 8; j++) {
                float2 bv = *reinterpret_cast<const float2*>(brow0 + j * H + h);
                a.x = fmaf(cc[j], bv.x, a.x); a.y = fmaf(cc[j], bv.y, a.y);
            }
            #pragma unroll
            for (int j = 0; j < 8; j++) {
                float2 bv = *reinterpret_cast<const float2*>(brow1 + j * H + h);
                a.x = fmaf(cc[8 + j], bv.x, a.x); a.y = fmaf(cc[8 + j], bv.y, a.y);
            }
            *reinterpret_cast<float2*>(op + h) = a;
        }
    }
}

extern "C" void kernel_launch(void* const* d_in, const int* in_sizes, int n_in,
                              void* d_out, int out_size, void* d_ws, size_t ws_size,
                              hipStream_t stream)
{
    const float* x  = (const float*)d_in[0];
    const float* bo = (const float*)d_in[1];
    const float* W1 = (const float*)d_in[2];
    const float* b1 = (const float*)d_in[3];
    const float* W2 = (const float*)d_in[4];
    const float* b2 = (const float*)d_in[5];
    const float* A  = (const float*)d_in[6];
    const float* Bm = (const float*)d_in[7];
    float* out = (float*)d_out;

    float* route_c   = (float*)d_ws;                                   // 32768*16 f32 = 2 MB
    int*   route_idx = (int*)((char*)d_ws + (size_t)NTOK * 16 * 4);    // 32768*2 i32 = 256 KB

    k_router<<<dim3(NTOK / BM), dim3(512), 0, stream>>>(
        x, W1, b1, W2, b2, A, route_c, route_idx);
    k_combine<<<dim3(256), dim3(512), 0, stream>>>(
        bo, Bm, route_c, route_idx, out);
}